// Round 1
// 1428.446 us; speedup vs baseline: 1.0041x; 1.0041x over previous
//
#include <hip/hip_runtime.h>
#include <math.h>

namespace {
constexpr int kS = 2048;
constexpr int kD = 64;
constexpr int kBH = 32;              // B*H = 2*16
constexpr int kTopK = 32;
constexpr int kPadBins = 2112;       // 2048 bins (11-bit) + 64 pad words
constexpr int kCandCap = 128;        // pivot-bin candidates (avg ~21 at 11-bit)
constexpr int kKeepCap = 64;         // kept (idx, weight) list cap
constexpr size_t kCtxElems  = (size_t)kBH * kS * kD;   // 4,194,304
constexpr size_t kAttnElems = (size_t)kBH * kS * kS;   // 134,217,728
}

__device__ __forceinline__ unsigned sortable_bits(float x) {
  unsigned u = __float_as_uint(x);
  return u ^ ((u & 0x80000000u) ? 0xFFFFFFFFu : 0x80000000u);
}

// ---------------------------------------------------------------------------
// Kernel 1: scores = Q K^T / 8, fp32.
// BIT-EXACTNESS INVARIANT: every score element is a single fp32 accumulator
// chain `acc += a*b` with k STRICTLY ASCENDING, scaled by 0.125f at the end.
// This round: K-dim staged in two 32-deep halves (LDS 67.6 -> 33.8 KB, so
// 3-4 blocks/CU instead of 2 = 12-16 waves/CU for latency hiding), and
// fragments loaded per-kk (a[8],b[8] instead of a[4][8],b[4][8]: live
// fragment VGPRs 64 -> 16). Chain order: k = half*32 + kk ascending 0..63,
// identical operands and fmac contraction -> bit-identical to prior rounds.
// ---------------------------------------------------------------------------
__global__ __launch_bounds__(256) void qk_scores(const float* __restrict__ q,
                                                 const float* __restrict__ k,
                                                 float* __restrict__ scores) {
  __shared__ float QsT[32][132];  // [kk][q-row]  16.9 KB
  __shared__ float KsT[32][132];  // [kk][k-row]  16.9 KB
  const int bh  = blockIdx.z;
  const int q0  = blockIdx.y * 128;
  const int k0  = blockIdx.x * 128;
  const int tid = threadIdx.x;
  const float* qg = q + ((size_t)bh * kS + q0) * kD;   // 128 rows x 64
  const float* kg = k + ((size_t)bh * kS + k0) * kD;

  const int ty8 = (tid >> 4) * 8;   // q rows ty8..ty8+7
  const int tx8 = (tid & 15) * 8;   // k cols tx8..tx8+7
  float acc[8][8] = {};

  for (int half = 0; half < 2; ++half) {
    if (half) __syncthreads();       // waves done reading previous half
#pragma unroll
    for (int rnd = 0; rnd < 4; ++rnd) {
      int flat = rnd * 1024 + tid * 4;   // 128 rows x 32 cols per half
      int r = flat >> 5;                 // tile row 0..127
      int c = flat & 31;                 // kk within half (mult of 4)
      float4 qv = *(const float4*)(qg + r * kD + half * 32 + c);
      QsT[c + 0][r] = qv.x;
      QsT[c + 1][r] = qv.y;
      QsT[c + 2][r] = qv.z;
      QsT[c + 3][r] = qv.w;
      float4 kv = *(const float4*)(kg + r * kD + half * 32 + c);
      KsT[c + 0][r] = kv.x;
      KsT[c + 1][r] = kv.y;
      KsT[c + 2][r] = kv.z;
      KsT[c + 3][r] = kv.w;
    }
    __syncthreads();

#pragma unroll
    for (int kk = 0; kk < 32; ++kk) {
      float a[8], b[8];
      *(float4*)(&a[0]) = *(const float4*)(&QsT[kk][ty8]);
      *(float4*)(&a[4]) = *(const float4*)(&QsT[kk][ty8 + 4]);
      *(float4*)(&b[0]) = *(const float4*)(&KsT[kk][tx8]);
      *(float4*)(&b[4]) = *(const float4*)(&KsT[kk][tx8 + 4]);
      // Per-element k order: half outer, kk inner ascending -> frozen chain.
#pragma unroll
      for (int i = 0; i < 8; ++i)
#pragma unroll
        for (int j = 0; j < 8; ++j)
          acc[i][j] += a[i] * b[j];
    }
  }

#pragma unroll
  for (int i = 0; i < 8; ++i) {
    float* orow = scores + ((size_t)bh * kS + q0 + ty8 + i) * kS + k0 + tx8;
    float4 o0 = make_float4(acc[i][0] * 0.125f, acc[i][1] * 0.125f,
                            acc[i][2] * 0.125f, acc[i][3] * 0.125f);
    float4 o1 = make_float4(acc[i][4] * 0.125f, acc[i][5] * 0.125f,
                            acc[i][6] * 0.125f, acc[i][7] * 0.125f);
    *(float4*)(orow)     = o0;
    *(float4*)(orow + 4) = o1;
  }
}

// ---------------------------------------------------------------------------
// Kernel 2: one WAVE per query row (4 rows / 256-thread block). No block
// barriers at all -- all communication is intra-wave (shuffles + per-wave LDS
// with lgkmcnt waits). Selection semantics identical to prior rounds:
//   t32 = 32nd-largest fp32 VALUE (duplicates counted), keep = score >= t32.
// 11-bit padded histogram: bin b lives at b + (b>>5), so each lane's 32-bin
// chunk (idx 33*lane + j) hits bank (lane+j)%32 -> conflict-free (was 32-way).
// ---------------------------------------------------------------------------
__global__ __launch_bounds__(256) void topk_softmax(const float* __restrict__ v,
                                                    float* __restrict__ ctx,
                                                    float* __restrict__ attn,
                                                    float* __restrict__ mask) {
  __shared__ unsigned s_hist[4][kPadBins];   // 33 KB (8.25 KB / wave)
  __shared__ float    s_cand[4][kCandCap];   // 2 KB
  __shared__ int      s_kidx[4][kKeepCap];   // 1 KB
  __shared__ float    s_kw[4][kKeepCap];     // 1 KB
  __shared__ unsigned s_nc[4], s_nk[4];

  const int tid  = threadIdx.x;
  const int wid  = tid >> 6;
  const int lane = tid & 63;
  const int row  = blockIdx.x * 4 + wid;     // bh*2048 + qi
  const int bh   = row >> 11;
  unsigned* hist = s_hist[wid];

  // P0: load this row's 2048 scores, 32/lane (8 x float4, coalesced).
  const float* srow = attn + (size_t)row * kS;   // scores from kernel 1
  float locv[32];
#pragma unroll
  for (int g = 0; g < 8; ++g)
    *(float4*)(&locv[g * 4]) = *(const float4*)(srow + g * 256 + lane * 4);

  // zero padded hist (2112 = 33*64, stride-64 -> 2-way = free) + counters
#pragma unroll
  for (int j = 0; j < 33; ++j) hist[j * 64 + lane] = 0u;
  if (lane == 0) { s_nc[wid] = 0u; s_nk[wid] = 0u; }

  // P1: histogram (11-bit sortable prefix) + row max.
  float pmax = locv[0];
#pragma unroll
  for (int j = 0; j < 32; ++j) {
    unsigned b = sortable_bits(locv[j]) >> 21;
    atomicAdd(&hist[b + (b >> 5)], 1u);
    pmax = fmaxf(pmax, locv[j]);
  }
#pragma unroll
  for (int off = 32; off >= 1; off >>= 1)
    pmax = fmaxf(pmax, __shfl_xor(pmax, off));

  asm volatile("s_waitcnt lgkmcnt(0)" ::: "memory");

  // P2: per-lane chunk sums (bins [32*lane, 32*lane+32)) + in-wave suffix scan.
  unsigned lsum = 0;
#pragma unroll
  for (int j = 0; j < 32; ++j) lsum += hist[lane * 33 + j];   // padded idx
  unsigned sfx = lsum;
#pragma unroll
  for (int off = 1; off < 64; off <<= 1) {
    unsigned z = __shfl_down(sfx, off);
    if (lane + off < 64) sfx += z;
  }
  const unsigned above = sfx - lsum;   // elements in chunks strictly above mine

  // P3: locate pivot bin (exactly one lane crosses kTopK).
  int bstar = 0, gabove = 0;
  const bool ispiv = (sfx >= (unsigned)kTopK) && (above < (unsigned)kTopK);
  if (ispiv) {
    unsigned run = above;
    for (int j = 31; j >= 0; --j) {
      unsigned h = hist[lane * 33 + j];
      if (run < (unsigned)kTopK && run + h >= (unsigned)kTopK) {
        bstar  = lane * 32 + j;
        gabove = (int)run;
      }
      run += h;
    }
  }
  const unsigned long long pm = __ballot(ispiv);
  const int psrc = __ffsll(pm) - 1;
  bstar  = __shfl(bstar, psrc);
  gabove = __shfl(gabove, psrc);

  // P4: collect pivot-bin candidates (equal values all share the pivot bin).
#pragma unroll
  for (int j = 0; j < 32; ++j) {
    unsigned b = sortable_bits(locv[j]) >> 21;
    if ((int)b == bstar) {
      unsigned p = atomicAdd(&s_nc[wid], 1u);
      if (p < (unsigned)kCandCap) s_cand[wid][p] = locv[j];
    }
  }
  asm volatile("s_waitcnt lgkmcnt(0)" ::: "memory");
  const int m = (int)min(s_nc[wid], (unsigned)kCandCap);

  // P5: t32 = value with gabove+g < 32 <= gabove+g+e. Lane i refines
  // candidates i and i+64; winner found via ballot, broadcast via shfl.
  const float x0 = (lane < m) ? s_cand[wid][lane] : 0.0f;
  const float x1 = (lane + 64 < m) ? s_cand[wid][lane + 64] : 0.0f;
  int g0 = 0, e0 = 0, g1 = 0, e1 = 0;
  for (int j = 0; j < m; ++j) {
    float y = s_cand[wid][j];   // broadcast read
    g0 += (y > x0); e0 += (y == x0);
    g1 += (y > x1); e1 += (y == x1);
  }
  const bool win0 = (lane < m) &&
                    (gabove + g0 < kTopK) && (gabove + g0 + e0 >= kTopK);
  const bool win1 = (lane + 64 < m) &&
                    (gabove + g1 < kTopK) && (gabove + g1 + e1 >= kTopK);
  const unsigned long long wm0 = __ballot(win0);
  const unsigned long long wm1 = __ballot(win1);
  float t32;
  if (wm0 != 0ull)      t32 = __shfl(x0, __ffsll(wm0) - 1);
  else if (wm1 != 0ull) t32 = __shfl(x1, __ffsll(wm1) - 1);
  else                  t32 = pmax;   // unreachable (cap never hit)

  // P6: weights, Z, kept-list for ctx. Same numerics as prior rounds:
  // w = __expf(score - rowmax) for kept, 0 otherwise.
  float w32[32];
  float psum = 0.0f;
#pragma unroll
  for (int j = 0; j < 32; ++j) {
    const bool keep = (locv[j] >= t32);
    const float wv = keep ? __expf(locv[j] - pmax) : 0.0f;
    w32[j] = wv;
    psum += wv;
    if (keep) {
      unsigned p = atomicAdd(&s_nk[wid], 1u);
      if (p < (unsigned)kKeepCap) {
        s_kidx[wid][p] = (j >> 2) * 256 + lane * 4 + (j & 3);  // key index
        s_kw[wid][p]   = wv;
      }
    }
  }
#pragma unroll
  for (int off = 32; off >= 1; off >>= 1)
    psum += __shfl_xor(psum, off);
  const float invZ = 1.0f / psum;

  // P7: write attn + mask straight from registers (coalesced float4).
  float* arow = attn + (size_t)row * kS;
  float* mrow = mask + (size_t)row * kS;
#pragma unroll
  for (int g = 0; g < 8; ++g) {
    float4 a = make_float4(w32[g*4+0] * invZ, w32[g*4+1] * invZ,
                           w32[g*4+2] * invZ, w32[g*4+3] * invZ);
    float4 mm = make_float4(locv[g*4+0] >= t32 ? 0.f : 1.f,
                            locv[g*4+1] >= t32 ? 0.f : 1.f,
                            locv[g*4+2] >= t32 ? 0.f : 1.f,
                            locv[g*4+3] >= t32 ? 0.f : 1.f);
    *(float4*)(arow + g * 256 + lane * 4) = a;
    *(float4*)(mrow + g * 256 + lane * 4) = mm;
  }

  // P8: context. ALL 64 lanes (lane = dim d), 4-way batched v loads (L2-hot),
  // single accumulator so fp add order stays list order (as prior rounds).
  asm volatile("s_waitcnt lgkmcnt(0)" ::: "memory");
  const int nk = (int)min(s_nk[wid], (unsigned)kKeepCap);
  const float* vb = v + ((size_t)bh * kS) * kD + lane;
  float acc = 0.0f;
  int c = 0;
  for (; c + 4 <= nk; c += 4) {
    const float w0 = s_kw[wid][c+0], w1 = s_kw[wid][c+1];
    const float w2 = s_kw[wid][c+2], w3 = s_kw[wid][c+3];
    const int   i0 = s_kidx[wid][c+0], i1 = s_kidx[wid][c+1];
    const int   i2 = s_kidx[wid][c+2], i3 = s_kidx[wid][c+3];
    const float v0 = vb[(size_t)i0 * kD], v1 = vb[(size_t)i1 * kD];
    const float v2 = vb[(size_t)i2 * kD], v3 = vb[(size_t)i3 * kD];
    acc += w0 * v0; acc += w1 * v1; acc += w2 * v2; acc += w3 * v3;
  }
  for (; c < nk; ++c)
    acc += s_kw[wid][c] * vb[(size_t)s_kidx[wid][c] * kD];
  ctx[(size_t)row * kD + lane] = acc * invZ;
}

extern "C" void kernel_launch(void* const* d_in, const int* in_sizes, int n_in,
                              void* d_out, int out_size, void* d_ws, size_t ws_size,
                              hipStream_t stream) {
  const float* q = (const float*)d_in[0];
  const float* k = (const float*)d_in[1];
  const float* v = (const float*)d_in[2];
  float* out  = (float*)d_out;
  float* ctx  = out;
  float* attn = out + kCtxElems;
  float* mask = attn + kAttnElems;

  dim3 g1(kS / 128, kS / 128, kBH);
  qk_scores<<<g1, 256, 0, stream>>>(q, k, attn);
  topk_softmax<<<dim3(kBH * kS / 4), 256, 0, stream>>>(v, ctx, attn, mask);
}

// Round 2
// 1374.199 us; speedup vs baseline: 1.0438x; 1.0395x over previous
//
#include <hip/hip_runtime.h>
#include <math.h>

namespace {
constexpr int kS = 2048;
constexpr int kD = 64;
constexpr int kBH = 32;              // B*H = 2*16
constexpr int kTopK = 32;
constexpr int kPadBins = 2112;       // 2048 bins (11-bit) + 64 pad words
constexpr int kCandCap = 128;        // pivot-bin candidates (avg ~21 at 11-bit)
constexpr int kKeepCap = 64;         // kept (idx, weight) list cap
constexpr size_t kCtxElems  = (size_t)kBH * kS * kD;   // 4,194,304
constexpr size_t kAttnElems = (size_t)kBH * kS * kS;   // 134,217,728
}

typedef float f2 __attribute__((ext_vector_type(2)));

__device__ __forceinline__ unsigned sortable_bits(float x) {
  unsigned u = __float_as_uint(x);
  return u ^ ((u & 0x80000000u) ? 0xFFFFFFFFu : 0x80000000u);
}

// ---------------------------------------------------------------------------
// Kernel 1: scores = Q K^T / 8, fp32.
// BIT-EXACTNESS INVARIANT: every score element is a single fp32 fused-FMA
// chain `acc += a*b` with k STRICTLY ASCENDING, scaled by 0.125f at the end.
// This round: accumulators paired along j as float2 ext-vectors so the
// compiler emits v_pk_fma_f32 (VOP3P packed fp32 FMA: 2 FLOP/lane/cyc, the
// only path to the 157 TF fp32 peak; scalar v_fmac tops at ~half). Each
// element of the pair is an INDEPENDENT fused chain with identical operands
// and order -> bit-identical to the scalar version.
// ---------------------------------------------------------------------------
__global__ __launch_bounds__(256) void qk_scores(const float* __restrict__ q,
                                                 const float* __restrict__ k,
                                                 float* __restrict__ scores) {
  __shared__ float QsT[32][132];  // [kk][q-row]  16.9 KB
  __shared__ float KsT[32][132];  // [kk][k-row]  16.9 KB
  const int bh  = blockIdx.z;
  const int q0  = blockIdx.y * 128;
  const int k0  = blockIdx.x * 128;
  const int tid = threadIdx.x;
  const float* qg = q + ((size_t)bh * kS + q0) * kD;   // 128 rows x 64
  const float* kg = k + ((size_t)bh * kS + k0) * kD;

  const int ty8 = (tid >> 4) * 8;   // q rows ty8..ty8+7
  const int tx8 = (tid & 15) * 8;   // k cols tx8..tx8+7
  f2 acc[8][4] = {};                // acc[i][j2] = cols {2*j2, 2*j2+1}

  for (int half = 0; half < 2; ++half) {
    if (half) __syncthreads();       // waves done reading previous half
#pragma unroll
    for (int rnd = 0; rnd < 4; ++rnd) {
      int flat = rnd * 1024 + tid * 4;   // 128 rows x 32 cols per half
      int r = flat >> 5;                 // tile row 0..127
      int c = flat & 31;                 // kk within half (mult of 4)
      float4 qv = *(const float4*)(qg + r * kD + half * 32 + c);
      QsT[c + 0][r] = qv.x;
      QsT[c + 1][r] = qv.y;
      QsT[c + 2][r] = qv.z;
      QsT[c + 3][r] = qv.w;
      float4 kv = *(const float4*)(kg + r * kD + half * 32 + c);
      KsT[c + 0][r] = kv.x;
      KsT[c + 1][r] = kv.y;
      KsT[c + 2][r] = kv.z;
      KsT[c + 3][r] = kv.w;
    }
    __syncthreads();

#pragma unroll
    for (int kk = 0; kk < 32; ++kk) {
      float a[8];
      f2 b[4];
      *(float4*)(&a[0]) = *(const float4*)(&QsT[kk][ty8]);
      *(float4*)(&a[4]) = *(const float4*)(&QsT[kk][ty8 + 4]);
      float4 b0 = *(const float4*)(&KsT[kk][tx8]);
      float4 b1 = *(const float4*)(&KsT[kk][tx8 + 4]);
      b[0] = f2{b0.x, b0.y};
      b[1] = f2{b0.z, b0.w};
      b[2] = f2{b1.x, b1.y};
      b[3] = f2{b1.z, b1.w};
      // Per-element k order: half outer, kk inner ascending -> frozen chain.
#pragma unroll
      for (int i = 0; i < 8; ++i) {
        const f2 as = {a[i], a[i]};
#pragma unroll
        for (int j2 = 0; j2 < 4; ++j2)
          acc[i][j2] += as * b[j2];    // -> v_pk_fma_f32 (2 fused chains)
      }
    }
  }

#pragma unroll
  for (int i = 0; i < 8; ++i) {
    float* orow = scores + ((size_t)bh * kS + q0 + ty8 + i) * kS + k0 + tx8;
    float4 o0 = make_float4(acc[i][0].x * 0.125f, acc[i][0].y * 0.125f,
                            acc[i][1].x * 0.125f, acc[i][1].y * 0.125f);
    float4 o1 = make_float4(acc[i][2].x * 0.125f, acc[i][2].y * 0.125f,
                            acc[i][3].x * 0.125f, acc[i][3].y * 0.125f);
    *(float4*)(orow)     = o0;
    *(float4*)(orow + 4) = o1;
  }
}

// ---------------------------------------------------------------------------
// Kernel 2: one WAVE per query row (4 rows / 256-thread block). No block
// barriers -- all communication intra-wave. Selection semantics frozen:
//   t32 = 32nd-largest fp32 VALUE (duplicates counted), keep = score >= t32.
// This round: kept-list built via ballot/popc compaction (removes 32
// serialized same-address LDS atomics per wave, makes ctx sum order
// deterministic), ctx gather batched 8-deep (halves latency-chained tail).
// ---------------------------------------------------------------------------
__global__ __launch_bounds__(256) void topk_softmax(const float* __restrict__ v,
                                                    float* __restrict__ ctx,
                                                    float* __restrict__ attn,
                                                    float* __restrict__ mask) {
  __shared__ unsigned s_hist[4][kPadBins];   // 33 KB (8.25 KB / wave)
  __shared__ float    s_cand[4][kCandCap];   // 2 KB
  __shared__ int      s_kidx[4][kKeepCap];   // 1 KB
  __shared__ float    s_kw[4][kKeepCap];     // 1 KB
  __shared__ unsigned s_nc[4];

  const int tid  = threadIdx.x;
  const int wid  = tid >> 6;
  const int lane = tid & 63;
  const int row  = blockIdx.x * 4 + wid;     // bh*2048 + qi
  const int bh   = row >> 11;
  unsigned* hist = s_hist[wid];

  // P0: load this row's 2048 scores, 32/lane (8 x float4, coalesced).
  const float* srow = attn + (size_t)row * kS;   // scores from kernel 1
  float locv[32];
#pragma unroll
  for (int g = 0; g < 8; ++g)
    *(float4*)(&locv[g * 4]) = *(const float4*)(srow + g * 256 + lane * 4);

  // zero padded hist (2112 = 33*64, stride-64 -> 2-way = free) + counter
#pragma unroll
  for (int j = 0; j < 33; ++j) hist[j * 64 + lane] = 0u;
  if (lane == 0) s_nc[wid] = 0u;

  // P1: histogram (11-bit sortable prefix) + row max.
  float pmax = locv[0];
#pragma unroll
  for (int j = 0; j < 32; ++j) {
    unsigned b = sortable_bits(locv[j]) >> 21;
    atomicAdd(&hist[b + (b >> 5)], 1u);
    pmax = fmaxf(pmax, locv[j]);
  }
#pragma unroll
  for (int off = 32; off >= 1; off >>= 1)
    pmax = fmaxf(pmax, __shfl_xor(pmax, off));

  asm volatile("s_waitcnt lgkmcnt(0)" ::: "memory");

  // P2: per-lane chunk sums (bins [32*lane, 32*lane+32)) + in-wave suffix scan.
  unsigned lsum = 0;
#pragma unroll
  for (int j = 0; j < 32; ++j) lsum += hist[lane * 33 + j];   // padded idx
  unsigned sfx = lsum;
#pragma unroll
  for (int off = 1; off < 64; off <<= 1) {
    unsigned z = __shfl_down(sfx, off);
    if (lane + off < 64) sfx += z;
  }
  const unsigned above = sfx - lsum;   // elements in chunks strictly above mine

  // P3: locate pivot bin (exactly one lane crosses kTopK).
  int bstar = 0, gabove = 0;
  const bool ispiv = (sfx >= (unsigned)kTopK) && (above < (unsigned)kTopK);
  if (ispiv) {
    unsigned run = above;
    for (int j = 31; j >= 0; --j) {
      unsigned h = hist[lane * 33 + j];
      if (run < (unsigned)kTopK && run + h >= (unsigned)kTopK) {
        bstar  = lane * 32 + j;
        gabove = (int)run;
      }
      run += h;
    }
  }
  const unsigned long long pm = __ballot(ispiv);
  const int psrc = __ffsll(pm) - 1;
  bstar  = __shfl(bstar, psrc);
  gabove = __shfl(gabove, psrc);

  // P4: collect pivot-bin candidates (equal values all share the pivot bin).
#pragma unroll
  for (int j = 0; j < 32; ++j) {
    unsigned b = sortable_bits(locv[j]) >> 21;
    if ((int)b == bstar) {
      unsigned p = atomicAdd(&s_nc[wid], 1u);
      if (p < (unsigned)kCandCap) s_cand[wid][p] = locv[j];
    }
  }
  asm volatile("s_waitcnt lgkmcnt(0)" ::: "memory");
  const int m = (int)min(s_nc[wid], (unsigned)kCandCap);

  // P5: t32 = value with gabove+g < 32 <= gabove+g+e. Lane i refines
  // candidates i and i+64; winner found via ballot, broadcast via shfl.
  const float x0 = (lane < m) ? s_cand[wid][lane] : 0.0f;
  const float x1 = (lane + 64 < m) ? s_cand[wid][lane + 64] : 0.0f;
  int g0 = 0, e0 = 0, g1 = 0, e1 = 0;
  for (int j = 0; j < m; ++j) {
    float y = s_cand[wid][j];   // broadcast read
    g0 += (y > x0); e0 += (y == x0);
    g1 += (y > x1); e1 += (y == x1);
  }
  const bool win0 = (lane < m) &&
                    (gabove + g0 < kTopK) && (gabove + g0 + e0 >= kTopK);
  const bool win1 = (lane + 64 < m) &&
                    (gabove + g1 < kTopK) && (gabove + g1 + e1 >= kTopK);
  const unsigned long long wm0 = __ballot(win0);
  const unsigned long long wm1 = __ballot(win1);
  float t32;
  if (wm0 != 0ull)      t32 = __shfl(x0, __ffsll(wm0) - 1);
  else if (wm1 != 0ull) t32 = __shfl(x1, __ffsll(wm1) - 1);
  else                  t32 = pmax;   // unreachable (cap never hit)

  // P6: weights, Z, kept-list via ballot/popc compaction (no LDS atomics;
  // deterministic j-major, lane-minor list order). Same numerics:
  // w = __expf(score - rowmax) for kept, 0 otherwise.
  const unsigned long long below = (1ull << lane) - 1ull;
  float w32[32];
  float psum = 0.0f;
  int nkbase = 0;
#pragma unroll
  for (int j = 0; j < 32; ++j) {
    const bool keep = (locv[j] >= t32);
    const float wv = keep ? __expf(locv[j] - pmax) : 0.0f;
    w32[j] = wv;
    psum += wv;
    const unsigned long long mk = __ballot(keep);
    if (keep) {
      const int slot = nkbase + (int)__popcll(mk & below);
      if (slot < kKeepCap) {
        s_kidx[wid][slot] = (j >> 2) * 256 + lane * 4 + (j & 3);  // key index
        s_kw[wid][slot]   = wv;
      }
    }
    nkbase += (int)__popcll(mk);
  }
  const int nk = nkbase < kKeepCap ? nkbase : kKeepCap;
#pragma unroll
  for (int off = 32; off >= 1; off >>= 1)
    psum += __shfl_xor(psum, off);
  const float invZ = 1.0f / psum;

  // P7: write attn + mask straight from registers (coalesced float4).
  float* arow = attn + (size_t)row * kS;
  float* mrow = mask + (size_t)row * kS;
#pragma unroll
  for (int g = 0; g < 8; ++g) {
    float4 a = make_float4(w32[g*4+0] * invZ, w32[g*4+1] * invZ,
                           w32[g*4+2] * invZ, w32[g*4+3] * invZ);
    float4 mm = make_float4(locv[g*4+0] >= t32 ? 0.f : 1.f,
                            locv[g*4+1] >= t32 ? 0.f : 1.f,
                            locv[g*4+2] >= t32 ? 0.f : 1.f,
                            locv[g*4+3] >= t32 ? 0.f : 1.f);
    *(float4*)(arow + g * 256 + lane * 4) = a;
    *(float4*)(mrow + g * 256 + lane * 4) = mm;
  }

  // P8: context. ALL 64 lanes (lane = dim d), 8-deep batched v loads (L2-hot,
  // coalesced 256B per row), single accumulator in deterministic slot order.
  asm volatile("s_waitcnt lgkmcnt(0)" ::: "memory");
  const float* vb = v + ((size_t)bh * kS) * kD + lane;
  float acc = 0.0f;
  int c = 0;
  for (; c + 8 <= nk; c += 8) {
    float w[8], vv[8];
    int   ii[8];
#pragma unroll
    for (int u = 0; u < 8; ++u) {
      w[u]  = s_kw[wid][c + u];
      ii[u] = s_kidx[wid][c + u];
    }
#pragma unroll
    for (int u = 0; u < 8; ++u)
      vv[u] = vb[(size_t)ii[u] * kD];
#pragma unroll
    for (int u = 0; u < 8; ++u)
      acc += w[u] * vv[u];
  }
  for (; c < nk; ++c)
    acc += s_kw[wid][c] * vb[(size_t)s_kidx[wid][c] * kD];
  ctx[(size_t)row * kD + lane] = acc * invZ;
}

extern "C" void kernel_launch(void* const* d_in, const int* in_sizes, int n_in,
                              void* d_out, int out_size, void* d_ws, size_t ws_size,
                              hipStream_t stream) {
  const float* q = (const float*)d_in[0];
  const float* k = (const float*)d_in[1];
  const float* v = (const float*)d_in[2];
  float* out  = (float*)d_out;
  float* ctx  = out;
  float* attn = out + kCtxElems;
  float* mask = attn + kAttnElems;

  dim3 g1(kS / 128, kS / 128, kBH);
  qk_scores<<<g1, 256, 0, stream>>>(q, k, attn);
  topk_softmax<<<dim3(kBH * kS / 4), 256, 0, stream>>>(v, ctx, attn, mask);
}